// Round 6
// baseline (311.381 us; speedup 1.0000x reference)
//
#include <hip/hip_runtime.h>
#include <hip/hip_bf16.h>
#include <math.h>

// MP_Attention: B=8,S=1024,E=1024,H=8,hd=128, fp32 in/out, bf16 MFMA internals.
// R6: attn rewritten around mfma_32x32x16 (32 q-rows/wave, QBLK=128) to halve
// LDS traffic per q (was LDS-throughput-bound at ~75us/CU). V stored in LDS
// with t-permuted layout so PV A-operand reads are single b128. GEMMs as R5.

typedef __attribute__((ext_vector_type(4))) float f32x4;
typedef __attribute__((ext_vector_type(16))) float f32x16;
typedef __attribute__((ext_vector_type(4))) short s16x4;
typedef __attribute__((ext_vector_type(8))) short s16x8;

__device__ __forceinline__ short f2bf(float f) {
  union { __hip_bfloat16 h; short s; } u;
  u.h = __float2bfloat16(f);
  return u.s;
}
__device__ __forceinline__ float bf2f(short s) {
  union { short s; __hip_bfloat16 h; } u;
  u.s = s;
  return __bfloat162float(u.h);
}
__device__ __forceinline__ f32x4 mfma16(s16x8 a, s16x8 b, f32x4 c) {
  return __builtin_amdgcn_mfma_f32_16x16x32_bf16(a, b, c, 0, 0, 0);
}
__device__ __forceinline__ f32x16 mfma32(s16x8 a, s16x8 b, f32x16 c) {
  return __builtin_amdgcn_mfma_f32_32x32x16_bf16(a, b, c, 0, 0, 0);
}

typedef __attribute__((address_space(1))) const unsigned int* as1_u32p;
typedef __attribute__((address_space(3))) unsigned int* as3_u32p;
__device__ __forceinline__ void g2l16(const short* g, short* l) {
  __builtin_amdgcn_global_load_lds((as1_u32p)g, (as3_u32p)l, 16, 0, 0);
}

#define ASM_VMCNT0 asm volatile("s_waitcnt vmcnt(0)" ::: "memory")
#define ASM_LGKM0  asm volatile("s_waitcnt lgkmcnt(0)" ::: "memory")
#define SFENCE     __builtin_amdgcn_sched_barrier(0)
#define BARRIER    __builtin_amdgcn_s_barrier()

// ---------------- weight norm: wn = w * g / (sqrt(1024)*eps + ||row||) ------
__global__ __launch_bounds__(256) void k_wnorm(const float* __restrict__ qw, const float* __restrict__ kw,
                                               const float* __restrict__ vw, const float* __restrict__ ow,
                                               const float* __restrict__ gain, short* __restrict__ wn) {
  const int r = blockIdx.x;            // 0..4095 (4 mats x 1024 rows)
  const int mat = r >> 10;
  const float* W = mat == 0 ? qw : mat == 1 ? kw : mat == 2 ? vw : ow;
  const float* src = W + (size_t)(r & 1023) * 1024;
  const int tid = threadIdx.x;
  f32x4 v = *(const f32x4*)&src[tid * 4];
  float s = v[0]*v[0] + v[1]*v[1] + v[2]*v[2] + v[3]*v[3];
  __shared__ float red[256];
  red[tid] = s; __syncthreads();
  for (int off = 128; off > 0; off >>= 1) {
    if (tid < off) red[tid] += red[tid + off];
    __syncthreads();
  }
  const float scale = gain[0] / (0.0032f + sqrtf(red[0]));
  s16x4 o;
  o[0] = f2bf(v[0]*scale); o[1] = f2bf(v[1]*scale);
  o[2] = f2bf(v[2]*scale); o[3] = f2bf(v[3]*scale);
  *(s16x4*)&wn[(size_t)r * 1024 + tid * 4] = o;
}

// ---------------- fp32 -> bf16 convert (query) ------------------------------
__global__ __launch_bounds__(256) void k_cvt(const float* __restrict__ in, short* __restrict__ out, int n4) {
  int idx = blockIdx.x * 256 + threadIdx.x;
  int stride = gridDim.x * 256;
  for (int i = idx; i < n4; i += stride) {
    f32x4 v = ((const f32x4*)in)[i];
    s16x4 o;
    o[0] = f2bf(v[0]); o[1] = f2bf(v[1]); o[2] = f2bf(v[2]); o[3] = f2bf(v[3]);
    ((s16x4*)out)[i] = o;
  }
}

// ---------------- bias * log2e -> bf16 (feeds exp2-domain softmax) ----------
__global__ __launch_bounds__(256) void k_scaleb(const float* __restrict__ in, short* __restrict__ out, int n4) {
  const float L2E = 1.4426950408889634f;
  int idx = blockIdx.x * 256 + threadIdx.x;
  int stride = gridDim.x * 256;
  for (int i = idx; i < n4; i += stride) {
    f32x4 v = ((const f32x4*)in)[i];
    s16x4 o;
    o[0] = f2bf(v[0]*L2E); o[1] = f2bf(v[1]*L2E);
    o[2] = f2bf(v[2]*L2E); o[3] = f2bf(v[3]*L2E);
    ((s16x4*)out)[i] = o;
  }
}

// ======== GEMM core loop: dbuf LDS + raw barrier, 1 barrier/K-step ==========
#define GEMM_K_LOOP(XPTR, WPTR)                                                      \
  const int srw = lane >> 3;          /* 0..7 row-in-chunk */                        \
  const int ssl = lane & 7;           /* 16B slot */                                 \
  const int ql7 = ql & 7;                                                            \
  {                                                                                  \
    _Pragma("unroll")                                                                \
    for (int i = 0; i < 4; i++) {                                                    \
      const int row = i * 32 + w * 8 + srw;                                          \
      g2l16(&XPTR[(size_t)(m0 + row) * 1024 + ((ssl ^ srw) << 3)],                   \
            &Al[0][(i * 32 + w * 8) * 64]);                                          \
      g2l16(&WPTR[(size_t)(n0 + row) * 1024 + ((ssl ^ srw) << 3)],                   \
            &Bl[0][(i * 32 + w * 8) * 64]);                                          \
    }                                                                                \
    ASM_VMCNT0; SFENCE; BARRIER; SFENCE;                                             \
    int bi = 0;                                                                      \
    for (int t = 0; t < 16; ++t) {                                                   \
      if (t < 15) {                                                                  \
        const int k1 = (t + 1) * 64;                                                 \
        _Pragma("unroll")                                                            \
        for (int i = 0; i < 4; i++) {                                                \
          const int row = i * 32 + w * 8 + srw;                                      \
          g2l16(&XPTR[(size_t)(m0 + row) * 1024 + k1 + ((ssl ^ srw) << 3)],          \
                &Al[bi ^ 1][(i * 32 + w * 8) * 64]);                                 \
          g2l16(&WPTR[(size_t)(n0 + row) * 1024 + k1 + ((ssl ^ srw) << 3)],          \
                &Bl[bi ^ 1][(i * 32 + w * 8) * 64]);                                 \
        }                                                                            \
      }                                                                              \
      const char* alp = (const char*)&Al[bi][0];                                     \
      const char* blp = (const char*)&Bl[bi][0];                                     \
      __builtin_amdgcn_s_setprio(1);                                                 \
      _Pragma("unroll")                                                              \
      for (int kc = 0; kc < 2; ++kc) {                                               \
        s16x8 af[4], bfr[4];                                                         \
        _Pragma("unroll")                                                            \
        for (int i = 0; i < 4; i++) {                                                \
          const int rA = wm * 64 + i * 16 + ql;                                      \
          af[i] = *(const s16x8*)(alp + rA * 128 +                                   \
                                  ((kc * 64 + 16 * hi) ^ (ql7 << 4)));               \
        }                                                                            \
        _Pragma("unroll")                                                            \
        for (int j = 0; j < 4; j++) {                                                \
          const int rB = wn_ * 64 + j * 16 + ql;                                     \
          bfr[j] = *(const s16x8*)(blp + rB * 128 +                                  \
                                   ((kc * 64 + 16 * hi) ^ (ql7 << 4)));              \
        }                                                                            \
        _Pragma("unroll")                                                            \
        for (int i = 0; i < 4; i++)                                                  \
          _Pragma("unroll")                                                          \
          for (int j = 0; j < 4; j++) acc[i][j] = mfma16(af[i], bfr[j], acc[i][j]);  \
      }                                                                              \
      __builtin_amdgcn_s_setprio(0);                                                 \
      ASM_VMCNT0; SFENCE; BARRIER; SFENCE;                                           \
      bi ^= 1;                                                                       \
    }                                                                                \
  }

// ---------------- QKV GEMM: C = X * WN^T  (z=0:Q, 1:K, 2:V-transposed) ------
__global__ __launch_bounds__(256) void k_gemm_qkv(const short* __restrict__ X, const short* __restrict__ WN,
                                                  short* __restrict__ Qb, short* __restrict__ Kb,
                                                  short* __restrict__ Vt) {
  __shared__ short Al[2][128 * 64];
  __shared__ short Bl[2][128 * 64];
  const int z = blockIdx.z;
  const short* __restrict__ Wm = WN + (size_t)z * 1048576;
  const int m0 = blockIdx.x * 128, n0 = blockIdx.y * 128;
  const int tid = threadIdx.x, lane = tid & 63, w = tid >> 6;
  const int hi = lane >> 4, ql = lane & 15;
  const int wm = w >> 1, wn_ = w & 1;
  f32x4 acc[4][4];
#pragma unroll
  for (int i = 0; i < 4; i++)
#pragma unroll
    for (int j = 0; j < 4; j++) acc[i][j] = (f32x4){0.f, 0.f, 0.f, 0.f};
  GEMM_K_LOOP(X, Wm)
  // epilogue via LDS bounce (32 KB = 128x128 bf16) for coalesced writes
  short* Cl = &Al[0][0];
  if (z == 2) {
    // store TRANSPOSED in LDS: Cl[ng_local][m_local]
#pragma unroll
    for (int i = 0; i < 4; i++) {
#pragma unroll
      for (int j = 0; j < 4; j++) {
        int col = wn_ * 64 + j * 16 + ql;
        int rowb = wm * 64 + i * 16 + 4 * hi;
#pragma unroll
        for (int r = 0; r < 4; r++) Cl[col * 128 + rowb + r] = f2bf(acc[i][j][r]);
      }
    }
    __syncthreads();
    const int b = m0 >> 10, sb = (m0 & 1023);
#pragma unroll
    for (int it = 0; it < 8; ++it) {
      int idx = tid + it * 256;
      int dl = idx >> 4, c = idx & 15;       // dl: 0..127 (n-local), c: 16B chunk
      int ng = n0 + dl, h = ng >> 7, d = ng & 127;
      *(s16x8*)&Vt[(size_t)((b * 8 + h) * 128 + d) * 1024 + sb + c * 8] =
          *(const s16x8*)&Cl[dl * 128 + c * 8];
    }
  } else {
    short* __restrict__ C = (z == 0) ? Qb : Kb;
#pragma unroll
    for (int i = 0; i < 4; i++) {
#pragma unroll
      for (int j = 0; j < 4; j++) {
        int col = wn_ * 64 + j * 16 + ql;
        int rowb = wm * 64 + i * 16 + 4 * hi;
#pragma unroll
        for (int r = 0; r < 4; r++) Cl[(rowb + r) * 128 + col] = f2bf(acc[i][j][r]);
      }
    }
    __syncthreads();
#pragma unroll
    for (int it = 0; it < 8; ++it) {
      int idx = tid + it * 256;
      int row = idx >> 4, c = idx & 15;
      *(s16x8*)&C[(size_t)(m0 + row) * 1024 + n0 + c * 8] = *(const s16x8*)&Cl[row * 128 + c * 8];
    }
  }
}

// ---------------- flash attention, 32x32 MFMA, 32 q-rows/wave ---------------
// K LDS [64][128] bf16, 16B-slot swizzle ^(row&7).
// V LDS [128 d][64 t] with t stored permuted: pi(t): t=ks*16+m*8+e' ->
//   pos = ks*16 + (e'>>2)*8 + m*4 + (e'&3); slot swizzle ^(d&7).
// PV A-read for (ks,hi2) is then ONE b128 at slot (ks*2+hi2).
__global__ __launch_bounds__(256) void k_attn(const short* __restrict__ Qb, const short* __restrict__ Kb,
                                              const short* __restrict__ Vt, const short* __restrict__ B2,
                                              short* __restrict__ Ob) {
  __shared__ short lds[64 * 128 + 128 * 64];   // 32 KB (K 16K + V 16K)
  short* Kl = lds;
  short* Vl = lds + 64 * 128;
  // XCD swizzle: nwg=512, 64/XCD -> 8 full bh per XCD (K/V L2 reuse)
  int f = blockIdx.x + (blockIdx.y << 3);
  f = (f & 7) * 64 + (f >> 3);
  const int bh = f >> 3, b = bh >> 3, h = bh & 7;
  const int q0 = (f & 7) * 128;
  const int tid = threadIdx.x, w = tid >> 6, lane = tid & 63;
  const int l31 = lane & 31, hi2 = lane >> 5, sw = l31 & 7;
  const int qrow = q0 + w * 32 + l31;
  const short* __restrict__ qbase = Qb + (size_t)(b * 1024 + qrow) * 1024 + h * 128;
  s16x8 qf[8];   // Q[qrow][kc*16 + hi2*8 + e]
#pragma unroll
  for (int kc = 0; kc < 8; kc++) qf[kc] = *(const s16x8*)&qbase[kc * 16 + hi2 * 8];
  float lsum = 0.f;
  f32x16 acc[4];
#pragma unroll
  for (int db = 0; db < 4; db++)
#pragma unroll
    for (int r = 0; r < 16; r++) acc[db][r] = 0.f;
  // scores bounded (|q.k|/sqrt(128) ~<15): exp2(st*sc2 + bias*log2e), no max.
  const float sc2 = (float)(0.08838834764831845 * 1.4426950408889634);
  const int krow_ = tid >> 4, kslot = tid & 15;           // K stage geometry
  const int vrow_ = tid >> 3, vslot = tid & 7;            // V stage geometry
  const int vks = vslot >> 1, vm = vslot & 1;
  const short* __restrict__ Kg = Kb + (size_t)(b * 1024) * 1024 + h * 128;
  const short* __restrict__ Vg = Vt + (size_t)bh * 128 * 1024;
  const short* __restrict__ Bg = B2 + (size_t)(h * 1024 + qrow) * 1024;

  s16x8 krA[4], vrA[4], krB[4], vrB[4];
#define LOADT(KR, VR, T0)                                                              \
  do {                                                                                 \
    _Pragma("unroll")                                                                  \
    for (int i = 0; i < 4; i++)                                                        \
      KR[i] = *(const s16x8*)&Kg[(size_t)((T0) + i * 16 + krow_) * 1024 + kslot * 8];  \
    _Pragma("unroll")                                                                  \
    for (int i = 0; i < 4; i++)                                                        \
      VR[i] = *(const s16x8*)&Vg[(size_t)(i * 32 + vrow_) * 1024 + (T0) + vslot * 8];  \
  } while (0)

#define STAGE(KR, VR)                                                                  \
  do {                                                                                 \
    _Pragma("unroll")                                                                  \
    for (int i = 0; i < 4; i++) {                                                      \
      int row = i * 16 + krow_;                                                        \
      *(s16x8*)((char*)Kl + row * 256 + ((kslot ^ (row & 7)) << 4)) = KR[i];           \
    }                                                                                  \
    _Pragma("unroll")                                                                  \
    for (int i = 0; i < 4; i++) {                                                      \
      int row = i * 32 + vrow_;                                                        \
      char* vb = (char*)Vl + row * 128;                                                \
      s16x4 lo, hi4;                                                                   \
      lo[0] = VR[i][0]; lo[1] = VR[i][1]; lo[2] = VR[i][2]; lo[3] = VR[i][3];          \
      hi4[0] = VR[i][4]; hi4[1] = VR[i][5]; hi4[2] = VR[i][6]; hi4[3] = VR[i][7];      \
      *(s16x4*)(vb + (((vks * 2) ^ (row & 7)) << 4) + vm * 8) = lo;                    \
      *(s16x4*)(vb + (((vks * 2 + 1) ^ (row & 7)) << 4) + vm * 8) = hi4;               \
    }                                                                                  \
  } while (0)

#define COMPUTE(T0)                                                                    \
  do {                                                                                 \
    s16x4 br[8];  /* bias: t = T0 + tb*32 + u*8 + 4*hi2 + j */                         \
    _Pragma("unroll")                                                                  \
    for (int tb = 0; tb < 2; tb++)                                                     \
      _Pragma("unroll")                                                                \
      for (int u = 0; u < 4; u++)                                                      \
        br[tb * 4 + u] = *(const s16x4*)&Bg[(T0) + tb * 32 + u * 8 + 4 * hi2];         \
    f32x16 st[2];                                                                      \
    __builtin_amdgcn_s_setprio(1);                                                     \
    _Pragma("unroll")                                                                  \
    for (int tb = 0; tb < 2; tb++) {                                                   \
      _Pragma("unroll")                                                                \
      for (int r = 0; r < 16; r++) st[tb][r] = 0.f;                                    \
      _Pragma("unroll")                                                                \
      for (int kc = 0; kc < 8; kc++) {                                                 \
        s16x8 kf = *(const s16x8*)((const char*)Kl + (tb * 32 + l31) * 256 +           \
                                   (((kc * 2 + hi2) ^ sw) << 4));                      \
        st[tb] = mfma32(kf, qf[kc], st[tb]);                                           \
      }                                                                                \
    }                                                                                  \
    __builtin_amdgcn_s_setprio(0);                                                     \
    _Pragma("unroll")                                                                  \
    for (int tb = 0; tb < 2; tb++)                                                     \
      _Pragma("unroll")                                                                \
      for (int r = 0; r < 16; r++) {                                                   \
        float e = exp2f(fmaf(st[tb][r], sc2, bf2f(br[tb * 4 + (r >> 2)][r & 3])));     \
        st[tb][r] = e;                                                                 \
        lsum += e;                                                                     \
      }                                                                                \
    s16x8 pf[4];  /* pf[ks][e] = P[t = ks*16 + (e&3)+8*(e>>2)+4*hi2] */                \
    _Pragma("unroll")                                                                  \
    for (int ks = 0; ks < 4; ks++)                                                     \
      _Pragma("unroll")                                                                \
      for (int e = 0; e < 8; e++)                                                      \
        pf[ks][e] = f2bf(st[ks >> 1][(e & 3) + 8 * (ks & 1) + 4 * (e >> 2)]);          \
    __builtin_amdgcn_s_setprio(1);                                                     \
    _Pragma("unroll")                                                                  \
    for (int db = 0; db < 4; db++)                                                     \
      _Pragma("unroll")                                                                \
      for (int ks = 0; ks < 4; ks++) {                                                 \
        s16x8 vf = *(const s16x8*)((const char*)Vl + (db * 32 + l31) * 128 +           \
                                   (((ks * 2 + hi2) ^ sw) << 4));                      \
        acc[db] = mfma32(vf, pf[ks], acc[db]);                                         \
      }                                                                                \
    __builtin_amdgcn_s_setprio(0);                                                     \
  } while (0)

  LOADT(krA, vrA, 0);
  for (int ih = 0; ih < 8; ++ih) {
    const int t0 = ih * 128;
    // ---- tile A (t0) ----
    ASM_VMCNT0; SFENCE;              // A loads arrived (in flight since prev compute)
    STAGE(krA, vrA);
    LOADT(krB, vrB, t0 + 64);        // issue B; stays in flight across barrier
    ASM_LGKM0; SFENCE; BARRIER; SFENCE;   // LDS visible; vmcnt NOT drained
    COMPUTE(t0);
    BARRIER; SFENCE;                 // all waves done reading LDS
    // ---- tile B (t0+64) ----
    ASM_VMCNT0; SFENCE;
    STAGE(krB, vrB);
    if (ih < 7) LOADT(krA, vrA, t0 + 128);
    ASM_LGKM0; SFENCE; BARRIER; SFENCE;
    COMPUTE(t0 + 64);
    BARRIER; SFENCE;
  }
  // reduce lsum (lanes 32 apart hold disjoint t-slices of same q)
  lsum += __shfl_xor(lsum, 32);
  const float invl = 1.f / lsum;
  __syncthreads();
  // epilogue: O[q][d] via swizzled LDS bounce [128 rows][128 d]
  short* Ol = lds;
  const int qloc = w * 32 + l31, qs = qloc & 7;
#pragma unroll
  for (int db = 0; db < 4; db++) {
#pragma unroll
    for (int u = 0; u < 4; u++) {
      int d0 = db * 32 + u * 8 + 4 * hi2;
      s16x4 v;
      v[0] = f2bf(acc[db][4 * u + 0] * invl);
      v[1] = f2bf(acc[db][4 * u + 1] * invl);
      v[2] = f2bf(acc[db][4 * u + 2] * invl);
      v[3] = f2bf(acc[db][4 * u + 3] * invl);
      *(s16x4*)((char*)Ol + qloc * 256 + (((d0 >> 3) ^ qs) << 4) + (d0 & 7) * 2) = v;
    }
  }
  __syncthreads();
#pragma unroll
  for (int it = 0; it < 8; ++it) {
    int idx = tid + it * 256;
    int row = idx >> 4, c = idx & 15;
    s16x8 vv = *(const s16x8*)((const char*)Ol + row * 256 + ((c ^ (row & 7)) << 4));
    *(s16x8*)&Ob[(size_t)(b * 1024 + q0 + row) * 1024 + h * 128 + c * 8] = vv;
  }
#undef LOADT
#undef STAGE
#undef COMPUTE
}

// ---------------- O-proj GEMM + fused mp_sum residual (fp32 out) ------------
__global__ __launch_bounds__(256) void k_gemm_o(const short* __restrict__ X, const short* __restrict__ Wm,
                                                const float* __restrict__ Qin, float* __restrict__ Out) {
  __shared__ short Al[2][128 * 64];
  __shared__ short Bl[2][128 * 64];
  const int m0 = blockIdx.x * 128, n0 = blockIdx.y * 128;
  const int tid = threadIdx.x, lane = tid & 63, w = tid >> 6;
  const int hi = lane >> 4, ql = lane & 15;
  const int wm = w >> 1, wn_ = w & 1;
  f32x4 acc[4][4];
#pragma unroll
  for (int i = 0; i < 4; i++)
#pragma unroll
    for (int j = 0; j < 4; j++) acc[i][j] = (f32x4){0.f, 0.f, 0.f, 0.f};
  GEMM_K_LOOP(X, Wm)
  // out = (query + o @ own^T) * 1/sqrt(2)   [t=0.5 mp_sum]
#pragma unroll
  for (int i = 0; i < 4; i++) {
    int mg = m0 + wm * 64 + i * 16 + 4 * hi;
#pragma unroll
    for (int j = 0; j < 4; j++) {
      int ng = n0 + wn_ * 64 + j * 16 + ql;
#pragma unroll
      for (int r = 0; r < 4; r++) {
        size_t idx = (size_t)(mg + r) * 1024 + ng;
        Out[idx] = (Qin[idx] + acc[i][j][r]) * 0.7071067811865476f;
      }
    }
  }
}

extern "C" void kernel_launch(void* const* d_in, const int* in_sizes, int n_in,
                              void* d_out, int out_size, void* d_ws, size_t ws_size,
                              hipStream_t stream) {
  (void)in_sizes; (void)n_in; (void)out_size; (void)ws_size;
  const float* query = (const float*)d_in[0];
  const float* gain_s = (const float*)d_in[1];
  // d_in[2] = gain_t (unused: time_dim=0)
  const float* qw = (const float*)d_in[3];
  const float* kw = (const float*)d_in[4];
  const float* vw = (const float*)d_in[5];
  const float* ow = (const float*)d_in[6];
  const float* bias = (const float*)d_in[7];
  float* out = (float*)d_out;

  // workspace (shorts): 4+8+8+8+8+8 = 44M shorts = 88 MB
  short* ws = (short*)d_ws;
  short* s_wn = ws;                       // 4 x 1M  (q,k,v,o normalized bf16)
  short* s_x  = s_wn + 4 * 1048576;       // 8M  query bf16; REUSED as attn output
  short* s_B2 = s_x + 8388608;            // 8M  bf16 bias * log2e
  short* s_Q  = s_B2 + 8388608;           // 8M
  short* s_K  = s_Q + 8388608;            // 8M
  short* s_Vt = s_K + 8388608;            // 8M  V transposed [b][h][d][s]
  short* s_O  = s_x;                      // alias: x dead after QKV GEMM

  k_wnorm<<<dim3(4096), dim3(256), 0, stream>>>(qw, kw, vw, ow, gain_s, s_wn);
  k_cvt<<<dim3(2048), dim3(256), 0, stream>>>(query, s_x, 2097152);
  k_scaleb<<<dim3(2048), dim3(256), 0, stream>>>(bias, s_B2, 2097152);
  k_gemm_qkv<<<dim3(64, 8, 3), dim3(256), 0, stream>>>(s_x, s_wn, s_Q, s_K, s_Vt);
  k_attn<<<dim3(8, 64), dim3(256), 0, stream>>>(s_Q, s_K, s_Vt, s_B2, s_O);
  k_gemm_o<<<dim3(64, 8), dim3(256), 0, stream>>>(s_O, s_wn + 3 * 1048576, query, out);
}

// Round 8
// 296.459 us; speedup vs baseline: 1.0503x; 1.0503x over previous
//
#include <hip/hip_runtime.h>
#include <hip/hip_bf16.h>
#include <math.h>

// MP_Attention: B=8,S=1024,E=1024,H=8,hd=128, fp32 in/out, bf16 MFMA internals.
// R8 (=R7 + k_prep coverage fix): GEMM K-loop is a 2-ahead counted-vmcnt
// pipeline (never drains in steady state); wnorm/cvt/scaleb fused into one
// k_prep dispatch (WITH grid-stride x4 in the cvt branches). Attn = R6.

typedef __attribute__((ext_vector_type(4))) float f32x4;
typedef __attribute__((ext_vector_type(16))) float f32x16;
typedef __attribute__((ext_vector_type(4))) short s16x4;
typedef __attribute__((ext_vector_type(8))) short s16x8;

__device__ __forceinline__ short f2bf(float f) {
  union { __hip_bfloat16 h; short s; } u;
  u.h = __float2bfloat16(f);
  return u.s;
}
__device__ __forceinline__ float bf2f(short s) {
  union { short s; __hip_bfloat16 h; } u;
  u.s = s;
  return __bfloat162float(u.h);
}
__device__ __forceinline__ f32x4 mfma16(s16x8 a, s16x8 b, f32x4 c) {
  return __builtin_amdgcn_mfma_f32_16x16x32_bf16(a, b, c, 0, 0, 0);
}
__device__ __forceinline__ f32x16 mfma32(s16x8 a, s16x8 b, f32x16 c) {
  return __builtin_amdgcn_mfma_f32_32x32x16_bf16(a, b, c, 0, 0, 0);
}

typedef __attribute__((address_space(1))) const unsigned int* as1_u32p;
typedef __attribute__((address_space(3))) unsigned int* as3_u32p;
__device__ __forceinline__ void g2l16(const short* g, short* l) {
  __builtin_amdgcn_global_load_lds((as1_u32p)g, (as3_u32p)l, 16, 0, 0);
}

#define ASM_VMCNT0 asm volatile("s_waitcnt vmcnt(0)" ::: "memory")
#define ASM_VMCNT8 asm volatile("s_waitcnt vmcnt(8)" ::: "memory")
#define ASM_LGKM0  asm volatile("s_waitcnt lgkmcnt(0)" ::: "memory")
#define SFENCE     __builtin_amdgcn_sched_barrier(0)
#define BARRIER    __builtin_amdgcn_s_barrier()

// ---------------- fused prep: weight-norm | query->bf16 | bias*log2e->bf16 --
__global__ __launch_bounds__(256) void k_prep(const float* __restrict__ qw, const float* __restrict__ kw,
                                              const float* __restrict__ vw, const float* __restrict__ ow,
                                              const float* __restrict__ gain, const float* __restrict__ query,
                                              const float* __restrict__ bias, short* __restrict__ wn,
                                              short* __restrict__ xq, short* __restrict__ b2) {
  __shared__ float red[256];
  const int bid = blockIdx.x, tid = threadIdx.x;
  if (bid < 4096) {
    // weight norm: wn = w * g / (sqrt(1024)*eps + ||row||)
    const int mat = bid >> 10;
    const float* W = mat == 0 ? qw : mat == 1 ? kw : mat == 2 ? vw : ow;
    const float* src = W + (size_t)(bid & 1023) * 1024;
    f32x4 v = *(const f32x4*)&src[tid * 4];
    float s = v[0]*v[0] + v[1]*v[1] + v[2]*v[2] + v[3]*v[3];
    red[tid] = s; __syncthreads();
    for (int off = 128; off > 0; off >>= 1) {
      if (tid < off) red[tid] += red[tid + off];
      __syncthreads();
    }
    const float scale = gain[0] / (0.0032f + sqrtf(red[0]));
    s16x4 o;
    o[0] = f2bf(v[0]*scale); o[1] = f2bf(v[1]*scale);
    o[2] = f2bf(v[2]*scale); o[3] = f2bf(v[3]*scale);
    *(s16x4*)&wn[(size_t)bid * 1024 + tid * 4] = o;
  } else if (bid < 6144) {
    // query fp32 -> bf16 (2,097,152 f32x4 elems; 2048 blocks x4 stride)
    for (int i = (bid - 4096) * 256 + tid; i < 2097152; i += 524288) {
      f32x4 v = ((const f32x4*)query)[i];
      s16x4 o;
      o[0] = f2bf(v[0]); o[1] = f2bf(v[1]); o[2] = f2bf(v[2]); o[3] = f2bf(v[3]);
      ((s16x4*)xq)[i] = o;
    }
  } else {
    // bias * log2e -> bf16 (2,097,152 f32x4 elems; 2048 blocks x4 stride)
    const float L2E = 1.4426950408889634f;
    for (int i = (bid - 6144) * 256 + tid; i < 2097152; i += 524288) {
      f32x4 v = ((const f32x4*)bias)[i];
      s16x4 o;
      o[0] = f2bf(v[0]*L2E); o[1] = f2bf(v[1]*L2E);
      o[2] = f2bf(v[2]*L2E); o[3] = f2bf(v[3]*L2E);
      ((s16x4*)b2)[i] = o;
    }
  }
}

// ======== GEMM core: 128x128 tile, BK=64, 2-ahead counted-vmcnt pipeline ====
// LDS 2x[128][64] shorts/operand; 16B-slot swizzle slot^=(row&7) applied on
// pre-swizzled global source (write side) and on ds_read (read side).
// Steady state: vmcnt(8) -> tile t landed (t+1's 8 loads still flying);
// stage(t+2) issued after post-compute barrier. Never drains to 0 mid-loop.
__device__ __forceinline__ void gemm_core(const short* __restrict__ X, const short* __restrict__ W_,
                                          int m0, int n0, int lane, int w, int hi, int ql,
                                          int wm, int wn_, short Al[2][8192], short Bl[2][8192],
                                          f32x4 acc[4][4]) {
  const int srw = lane >> 3, ssl = lane & 7, ql7 = ql & 7;
  auto stage8 = [&](int BI, int K0) {
#pragma unroll
    for (int i = 0; i < 4; i++) {
      const int row = i * 32 + w * 8 + srw;
      g2l16(&X[(size_t)(m0 + row) * 1024 + K0 + ((ssl ^ srw) << 3)],
            &Al[BI][(i * 32 + w * 8) * 64]);
      g2l16(&W_[(size_t)(n0 + row) * 1024 + K0 + ((ssl ^ srw) << 3)],
            &Bl[BI][(i * 32 + w * 8) * 64]);
    }
  };
  auto compute_tile = [&](int BI) {
    const char* alp = (const char*)&Al[BI][0];
    const char* blp = (const char*)&Bl[BI][0];
    __builtin_amdgcn_s_setprio(1);
#pragma unroll
    for (int kc = 0; kc < 2; ++kc) {
      s16x8 af[4], bfr[4];
#pragma unroll
      for (int i = 0; i < 4; i++) {
        const int rA = wm * 64 + i * 16 + ql;
        af[i] = *(const s16x8*)(alp + rA * 128 + ((kc * 64 + 16 * hi) ^ (ql7 << 4)));
      }
#pragma unroll
      for (int j = 0; j < 4; j++) {
        const int rB = wn_ * 64 + j * 16 + ql;
        bfr[j] = *(const s16x8*)(blp + rB * 128 + ((kc * 64 + 16 * hi) ^ (ql7 << 4)));
      }
#pragma unroll
      for (int i = 0; i < 4; i++)
#pragma unroll
        for (int j = 0; j < 4; j++) acc[i][j] = mfma16(af[i], bfr[j], acc[i][j]);
    }
    __builtin_amdgcn_s_setprio(0);
  };
  stage8(0, 0);
  stage8(1, 64);
  int bi = 0;
  for (int t = 0; t < 15; ++t) {
    ASM_VMCNT8; SFENCE; BARRIER; SFENCE;   // tile t landed; t+1 still flying
    compute_tile(bi);
    SFENCE; BARRIER; SFENCE;               // all waves done reading buf bi
    if (t < 14) stage8(bi, (t + 2) * 64);  // overwrite just-freed buffer
    bi ^= 1;
  }
  ASM_VMCNT0; SFENCE; BARRIER; SFENCE;     // last tile (no newer loads behind it)
  compute_tile(bi);                         // bi==1: epilogue may reuse Al[0]
}

// ---------------- QKV GEMM: C = X * WN^T  (z=0:Q, 1:K, 2:V-transposed) ------
__global__ __launch_bounds__(256) void k_gemm_qkv(const short* __restrict__ X, const short* __restrict__ WN,
                                                  short* __restrict__ Qb, short* __restrict__ Kb,
                                                  short* __restrict__ Vt) {
  __shared__ short Al[2][128 * 64];
  __shared__ short Bl[2][128 * 64];
  const int z = blockIdx.z;
  const short* __restrict__ Wm = WN + (size_t)z * 1048576;
  const int m0 = blockIdx.x * 128, n0 = blockIdx.y * 128;
  const int tid = threadIdx.x, lane = tid & 63, w = tid >> 6;
  const int hi = lane >> 4, ql = lane & 15;
  const int wm = w >> 1, wn_ = w & 1;
  f32x4 acc[4][4];
#pragma unroll
  for (int i = 0; i < 4; i++)
#pragma unroll
    for (int j = 0; j < 4; j++) acc[i][j] = (f32x4){0.f, 0.f, 0.f, 0.f};
  gemm_core(X, Wm, m0, n0, lane, w, hi, ql, wm, wn_, Al, Bl, acc);
  // epilogue via LDS bounce (32 KB = 128x128 bf16) for coalesced writes
  short* Cl = &Al[0][0];
  if (z == 2) {
    // store TRANSPOSED in LDS: Cl[ng_local][m_local]
#pragma unroll
    for (int i = 0; i < 4; i++) {
#pragma unroll
      for (int j = 0; j < 4; j++) {
        int col = wn_ * 64 + j * 16 + ql;
        int rowb = wm * 64 + i * 16 + 4 * hi;
#pragma unroll
        for (int r = 0; r < 4; r++) Cl[col * 128 + rowb + r] = f2bf(acc[i][j][r]);
      }
    }
    __syncthreads();
    const int b = m0 >> 10, sb = (m0 & 1023);
#pragma unroll
    for (int it = 0; it < 8; ++it) {
      int idx = tid + it * 256;
      int dl = idx >> 4, c = idx & 15;       // dl: 0..127 (n-local), c: 16B chunk
      int ng = n0 + dl, h = ng >> 7, d = ng & 127;
      *(s16x8*)&Vt[(size_t)((b * 8 + h) * 128 + d) * 1024 + sb + c * 8] =
          *(const s16x8*)&Cl[dl * 128 + c * 8];
    }
  } else {
    short* __restrict__ C = (z == 0) ? Qb : Kb;
#pragma unroll
    for (int i = 0; i < 4; i++) {
#pragma unroll
      for (int j = 0; j < 4; j++) {
        int col = wn_ * 64 + j * 16 + ql;
        int rowb = wm * 64 + i * 16 + 4 * hi;
#pragma unroll
        for (int r = 0; r < 4; r++) Cl[(rowb + r) * 128 + col] = f2bf(acc[i][j][r]);
      }
    }
    __syncthreads();
#pragma unroll
    for (int it = 0; it < 8; ++it) {
      int idx = tid + it * 256;
      int row = idx >> 4, c = idx & 15;
      *(s16x8*)&C[(size_t)(m0 + row) * 1024 + n0 + c * 8] = *(const s16x8*)&Cl[row * 128 + c * 8];
    }
  }
}

// ---------------- flash attention, 32x32 MFMA, 32 q-rows/wave (R6) ----------
__global__ __launch_bounds__(256) void k_attn(const short* __restrict__ Qb, const short* __restrict__ Kb,
                                              const short* __restrict__ Vt, const short* __restrict__ B2,
                                              short* __restrict__ Ob) {
  __shared__ short lds[64 * 128 + 128 * 64];   // 32 KB (K 16K + V 16K)
  short* Kl = lds;
  short* Vl = lds + 64 * 128;
  // XCD swizzle: nwg=512, 64/XCD -> 8 full bh per XCD (K/V L2 reuse)
  int f = blockIdx.x + (blockIdx.y << 3);
  f = (f & 7) * 64 + (f >> 3);
  const int bh = f >> 3, b = bh >> 3, h = bh & 7;
  const int q0 = (f & 7) * 128;
  const int tid = threadIdx.x, w = tid >> 6, lane = tid & 63;
  const int l31 = lane & 31, hi2 = lane >> 5, sw = l31 & 7;
  const int qrow = q0 + w * 32 + l31;
  const short* __restrict__ qbase = Qb + (size_t)(b * 1024 + qrow) * 1024 + h * 128;
  s16x8 qf[8];   // Q[qrow][kc*16 + hi2*8 + e]
#pragma unroll
  for (int kc = 0; kc < 8; kc++) qf[kc] = *(const s16x8*)&qbase[kc * 16 + hi2 * 8];
  float lsum = 0.f;
  f32x16 acc[4];
#pragma unroll
  for (int db = 0; db < 4; db++)
#pragma unroll
    for (int r = 0; r < 16; r++) acc[db][r] = 0.f;
  const float sc2 = (float)(0.08838834764831845 * 1.4426950408889634);
  const int krow_ = tid >> 4, kslot = tid & 15;
  const int vrow_ = tid >> 3, vslot = tid & 7;
  const int vks = vslot >> 1, vm = vslot & 1;
  const short* __restrict__ Kg = Kb + (size_t)(b * 1024) * 1024 + h * 128;
  const short* __restrict__ Vg = Vt + (size_t)bh * 128 * 1024;
  const short* __restrict__ Bg = B2 + (size_t)(h * 1024 + qrow) * 1024;

  s16x8 krA[4], vrA[4], krB[4], vrB[4];
#define LOADT(KR, VR, T0)                                                              \
  do {                                                                                 \
    _Pragma("unroll")                                                                  \
    for (int i = 0; i < 4; i++)                                                        \
      KR[i] = *(const s16x8*)&Kg[(size_t)((T0) + i * 16 + krow_) * 1024 + kslot * 8];  \
    _Pragma("unroll")                                                                  \
    for (int i = 0; i < 4; i++)                                                        \
      VR[i] = *(const s16x8*)&Vg[(size_t)(i * 32 + vrow_) * 1024 + (T0) + vslot * 8];  \
  } while (0)

#define STAGE(KR, VR)                                                                  \
  do {                                                                                 \
    _Pragma("unroll")                                                                  \
    for (int i = 0; i < 4; i++) {                                                      \
      int row = i * 16 + krow_;                                                        \
      *(s16x8*)((char*)Kl + row * 256 + ((kslot ^ (row & 7)) << 4)) = KR[i];           \
    }                                                                                  \
    _Pragma("unroll")                                                                  \
    for (int i = 0; i < 4; i++) {                                                      \
      int row = i * 32 + vrow_;                                                        \
      char* vb = (char*)Vl + row * 128;                                                \
      s16x4 lo, hi4;                                                                   \
      lo[0] = VR[i][0]; lo[1] = VR[i][1]; lo[2] = VR[i][2]; lo[3] = VR[i][3];          \
      hi4[0] = VR[i][4]; hi4[1] = VR[i][5]; hi4[2] = VR[i][6]; hi4[3] = VR[i][7];      \
      *(s16x4*)(vb + (((vks * 2) ^ (row & 7)) << 4) + vm * 8) = lo;                    \
      *(s16x4*)(vb + (((vks * 2 + 1) ^ (row & 7)) << 4) + vm * 8) = hi4;               \
    }                                                                                  \
  } while (0)

#define COMPUTE(T0)                                                                    \
  do {                                                                                 \
    s16x4 br[8];  /* bias: t = T0 + tb*32 + u*8 + 4*hi2 + j */                         \
    _Pragma("unroll")                                                                  \
    for (int tb = 0; tb < 2; tb++)                                                     \
      _Pragma("unroll")                                                                \
      for (int u = 0; u < 4; u++)                                                      \
        br[tb * 4 + u] = *(const s16x4*)&Bg[(T0) + tb * 32 + u * 8 + 4 * hi2];         \
    f32x16 st[2];                                                                      \
    __builtin_amdgcn_s_setprio(1);                                                     \
    _Pragma("unroll")                                                                  \
    for (int tb = 0; tb < 2; tb++) {                                                   \
      _Pragma("unroll")                                                                \
      for (int r = 0; r < 16; r++) st[tb][r] = 0.f;                                    \
      _Pragma("unroll")                                                                \
      for (int kc = 0; kc < 8; kc++) {                                                 \
        s16x8 kf = *(const s16x8*)((const char*)Kl + (tb * 32 + l31) * 256 +           \
                                   (((kc * 2 + hi2) ^ sw) << 4));                      \
        st[tb] = mfma32(kf, qf[kc], st[tb]);                                           \
      }                                                                                \
    }                                                                                  \
    __builtin_amdgcn_s_setprio(0);                                                     \
    _Pragma("unroll")                                                                  \
    for (int tb = 0; tb < 2; tb++)                                                     \
      _Pragma("unroll")                                                                \
      for (int r = 0; r < 16; r++) {                                                   \
        float e = exp2f(fmaf(st[tb][r], sc2, bf2f(br[tb * 4 + (r >> 2)][r & 3])));     \
        st[tb][r] = e;                                                                 \
        lsum += e;                                                                     \
      }                                                                                \
    s16x8 pf[4];  /* pf[ks][e] = P[t = ks*16 + (e&3)+8*(e>>2)+4*hi2] */                \
    _Pragma("unroll")                                                                  \
    for (int ks = 0; ks < 4; ks++)                                                     \
      _Pragma("unroll")                                                                \
      for (int e = 0; e < 8; e++)                                                      \
        pf[ks][e] = f2bf(st[ks >> 1][(e & 3) + 8 * (ks & 1) + 4 * (e >> 2)]);          \
    __builtin_amdgcn_s_setprio(1);                                                     \
    _Pragma("unroll")                                                                  \
    for (int db = 0; db < 4; db++)                                                     \
      _Pragma("unroll")                                                                \
      for (int ks = 0; ks < 4; ks++) {                                                 \
        s16x8 vf = *(const s16x8*)((const char*)Vl + (db * 32 + l31) * 128 +           \
                                   (((ks * 2 + hi2) ^ sw) << 4));                      \
        acc[db] = mfma32(vf, pf[ks], acc[db]);                                         \
      }                                                                                \
    __builtin_amdgcn_s_setprio(0);                                                     \
  } while (0)

  LOADT(krA, vrA, 0);
  for (int ih = 0; ih < 8; ++ih) {
    const int t0 = ih * 128;
    // ---- tile A (t0) ----
    ASM_VMCNT0; SFENCE;              // A loads arrived (in flight since prev compute)
    STAGE(krA, vrA);
    LOADT(krB, vrB, t0 + 64);        // issue B; stays in flight across barrier
    ASM_LGKM0; SFENCE; BARRIER; SFENCE;   // LDS visible; vmcnt NOT drained
    COMPUTE(t0);
    BARRIER; SFENCE;                 // all waves done reading LDS
    // ---- tile B (t0+64) ----
    ASM_VMCNT0; SFENCE;
    STAGE(krB, vrB);
    if (ih < 7) LOADT(krA, vrA, t0 + 128);
    ASM_LGKM0; SFENCE; BARRIER; SFENCE;
    COMPUTE(t0 + 64);
    BARRIER; SFENCE;
  }
  // reduce lsum (lanes 32 apart hold disjoint t-slices of same q)
  lsum += __shfl_xor(lsum, 32);
  const float invl = 1.f / lsum;
  __syncthreads();
  // epilogue: O[q][d] via swizzled LDS bounce [128 rows][128 d]
  short* Ol = lds;
  const int qloc = w * 32 + l31, qs = qloc & 7;
#pragma unroll
  for (int db = 0; db < 4; db++) {
#pragma unroll
    for (int u = 0; u < 4; u++) {
      int d0 = db * 32 + u * 8 + 4 * hi2;
      s16x4 v;
      v[0] = f2bf(acc[db][4 * u + 0] * invl);
      v[1] = f2bf(acc[db][4 * u + 1] * invl);
      v[2] = f2bf(acc[db][4 * u + 2] * invl);
      v[3] = f2bf(acc[db][4 * u + 3] * invl);
      *(s16x4*)((char*)Ol + qloc * 256 + (((d0 >> 3) ^ qs) << 4) + (d0 & 7) * 2) = v;
    }
  }
  __syncthreads();
#pragma unroll
  for (int it = 0; it < 8; ++it) {
    int idx = tid + it * 256;
    int row = idx >> 4, c = idx & 15;
    s16x8 vv = *(const s16x8*)((const char*)Ol + row * 256 + ((c ^ (row & 7)) << 4));
    *(s16x8*)&Ob[(size_t)(b * 1024 + q0 + row) * 1024 + h * 128 + c * 8] = vv;
  }
#undef LOADT
#undef STAGE
#undef COMPUTE
}

// ---------------- O-proj GEMM + fused mp_sum residual (fp32 out) ------------
__global__ __launch_bounds__(256) void k_gemm_o(const short* __restrict__ X, const short* __restrict__ Wm,
                                                const float* __restrict__ Qin, float* __restrict__ Out) {
  __shared__ short Al[2][128 * 64];
  __shared__ short Bl[2][128 * 64];
  const int m0 = blockIdx.x * 128, n0 = blockIdx.y * 128;
  const int tid = threadIdx.x, lane = tid & 63, w = tid >> 6;
  const int hi = lane >> 4, ql = lane & 15;
  const int wm = w >> 1, wn_ = w & 1;
  f32x4 acc[4][4];
#pragma unroll
  for (int i = 0; i < 4; i++)
#pragma unroll
    for (int j = 0; j < 4; j++) acc[i][j] = (f32x4){0.f, 0.f, 0.f, 0.f};
  gemm_core(X, Wm, m0, n0, lane, w, hi, ql, wm, wn_, Al, Bl, acc);
  // out = (query + o @ own^T) * 1/sqrt(2)   [t=0.5 mp_sum]
#pragma unroll
  for (int i = 0; i < 4; i++) {
    int mg = m0 + wm * 64 + i * 16 + 4 * hi;
#pragma unroll
    for (int j = 0; j < 4; j++) {
      int ng = n0 + wn_ * 64 + j * 16 + ql;
#pragma unroll
      for (int r = 0; r < 4; r++) {
        size_t idx = (size_t)(mg + r) * 1024 + ng;
        Out[idx] = (Qin[idx] + acc[i][j][r]) * 0.7071067811865476f;
      }
    }
  }
}

extern "C" void kernel_launch(void* const* d_in, const int* in_sizes, int n_in,
                              void* d_out, int out_size, void* d_ws, size_t ws_size,
                              hipStream_t stream) {
  (void)in_sizes; (void)n_in; (void)out_size; (void)ws_size;
  const float* query = (const float*)d_in[0];
  const float* gain_s = (const float*)d_in[1];
  // d_in[2] = gain_t (unused: time_dim=0)
  const float* qw = (const float*)d_in[3];
  const float* kw = (const float*)d_in[4];
  const float* vw = (const float*)d_in[5];
  const float* ow = (const float*)d_in[6];
  const float* bias = (const float*)d_in[7];
  float* out = (float*)d_out;

  // workspace (shorts): 4+8+8+8+8+8 = 44M shorts = 88 MB
  short* ws = (short*)d_ws;
  short* s_wn = ws;                       // 4 x 1M  (q,k,v,o normalized bf16)
  short* s_x  = s_wn + 4 * 1048576;       // 8M  query bf16; REUSED as attn output
  short* s_B2 = s_x + 8388608;            // 8M  bf16 bias * log2e
  short* s_Q  = s_B2 + 8388608;           // 8M
  short* s_K  = s_Q + 8388608;            // 8M
  short* s_Vt = s_K + 8388608;            // 8M  V transposed [b][h][d][s]
  short* s_O  = s_x;                      // alias: x dead after QKV GEMM

  k_prep<<<dim3(8192), dim3(256), 0, stream>>>(qw, kw, vw, ow, gain_s, query, bias, s_wn, s_x, s_B2);
  k_gemm_qkv<<<dim3(64, 8, 3), dim3(256), 0, stream>>>(s_x, s_wn, s_Q, s_K, s_Vt);
  k_attn<<<dim3(8, 64), dim3(256), 0, stream>>>(s_Q, s_K, s_Vt, s_B2, s_O);
  k_gemm_o<<<dim3(64, 8), dim3(256), 0, stream>>>(s_O, s_wn + 3 * 1048576, query, out);
}